// Round 7
// baseline (44.161 us; speedup 1.0000x reference)
//
#include <hip/hip_runtime.h>
#include <stdint.h>

#define TT 128
#define HH 256
#define WW 256
#define PLANE (TT*HH*WW)            // 8388608 elems / channel
#define FRAME (HH*WW)               // 65536 px / frame
#define ROWS 32                     // tile rows
#define TPF  (HH/ROWS)              // 8 tiles per frame
#define REPEAT 4                    // tiles per block (pipelined)
#define HALO 5
#define BROWS (ROWS + 2*HALO)       // 42 buffered rows (fits one wave)
#define THRESH 0.5f

typedef float nfloat4 __attribute__((ext_vector_type(4)));

__device__ __forceinline__ uint64_t shfl64(uint64_t v, int src) {
    uint32_t lo = (uint32_t)v, hi = (uint32_t)(v >> 32);
    lo = __shfl(lo, src);
    hi = __shfl(hi, src);
    return ((uint64_t)hi << 32) | lo;
}

// OR-combine 16 lanes' nibbles into one u64 row-word. col = 64*(l>>4)+4*(l&15)+p.
__device__ __forceinline__ uint64_t pack16(uint32_t nib) {
    int lane = threadIdx.x & 63;
    uint64_t v = (uint64_t)nib << (4 * (lane & 15));
    v |= __shfl_xor(v, 1);
    v |= __shfl_xor(v, 2);
    v |= __shfl_xor(v, 4);
    v |= __shfl_xor(v, 8);
    return v;
}

// Mask nibble for 4 pixels at (frame t, row gr, cols 4*col4..+3).
// Out-of-frame rows -> 0. Same f32 add order as numpy: (d0+d1)+d2.
__device__ __forceinline__ uint32_t mask_nib(const float* __restrict__ X,
                                             const float* __restrict__ bg,
                                             int t, int gr, int col4) {
    if (gr < 0 || gr >= HH) return 0u;
    size_t pix = (size_t)t * FRAME + (size_t)gr * WW + 4 * col4;
    nfloat4 x0 = *(const nfloat4*)(X + pix);
    nfloat4 x1 = *(const nfloat4*)(X + (size_t)PLANE + pix);
    nfloat4 x2 = *(const nfloat4*)(X + 2 * (size_t)PLANE + pix);
    const nfloat4* bp = (const nfloat4*)(bg + ((size_t)gr * WW + 4 * col4) * 3);
    nfloat4 q0 = bp[0], q1 = bp[1], q2 = bp[2];
    uint32_t nib = 0;
    nib |= ((fabsf(x0[0] - q0[0]) + fabsf(x1[0] - q0[1]) + fabsf(x2[0] - q0[2])) > THRESH) ? 1u : 0u;
    nib |= ((fabsf(x0[1] - q0[3]) + fabsf(x1[1] - q1[0]) + fabsf(x2[1] - q1[1])) > THRESH) ? 2u : 0u;
    nib |= ((fabsf(x0[2] - q1[2]) + fabsf(x1[2] - q1[3]) + fabsf(x2[2] - q2[0])) > THRESH) ? 4u : 0u;
    nib |= ((fabsf(x0[3] - q2[1]) + fabsf(x1[3] - q2[2]) + fabsf(x2[3] - q2[3])) > THRESH) ? 8u : 0u;
    return nib;
}

__global__ __launch_bounds__(512) void fused_kernel(const float* __restrict__ X,
                                                    const float* __restrict__ bg,
                                                    float* __restrict__ out) {
    __shared__ uint64_t mbuf[2][BROWS][4];      // double-buffered mask bits, 2688 B
    const int t    = blockIdx.x >> 1;           // frame
    const int j0   = (blockIdx.x & 1) * REPEAT; // first tile of this block's half
    const int tid  = threadIdx.x;
    const int lane = tid & 63;
    const int wave = tid >> 6;                  // 0..7
    const int col4 = lane;                      // float4-column 0..63

#pragma unroll
    for (int rep = 0; rep < REPEAT; ++rep) {
        const int r0 = (j0 + rep) * ROWS;
        uint64_t (*B)[4] = mbuf[rep & 1];       // compile-time after unroll

        // ---- phase 1: main tile loads (overlap previous tile's NT stores) ----
        nfloat4 xv[4][3];
        uint32_t nib[4];
#pragma unroll
        for (int k = 0; k < 4; ++k) {
            const int gr = r0 + wave + 8 * k;
            size_t pix = (size_t)t * FRAME + (size_t)gr * WW + 4 * col4;
            xv[k][0] = *(const nfloat4*)(X + pix);
            xv[k][1] = *(const nfloat4*)(X + (size_t)PLANE + pix);
            xv[k][2] = *(const nfloat4*)(X + 2 * (size_t)PLANE + pix);
            const nfloat4* bp = (const nfloat4*)(bg + ((size_t)gr * WW + 4 * col4) * 3);
            nfloat4 q0 = bp[0], q1 = bp[1], q2 = bp[2];
            uint32_t nb = 0;
            nb |= ((fabsf(xv[k][0][0] - q0[0]) + fabsf(xv[k][1][0] - q0[1]) + fabsf(xv[k][2][0] - q0[2])) > THRESH) ? 1u : 0u;
            nb |= ((fabsf(xv[k][0][1] - q0[3]) + fabsf(xv[k][1][1] - q1[0]) + fabsf(xv[k][2][1] - q1[1])) > THRESH) ? 2u : 0u;
            nb |= ((fabsf(xv[k][0][2] - q1[2]) + fabsf(xv[k][1][2] - q1[3]) + fabsf(xv[k][2][2] - q2[0])) > THRESH) ? 4u : 0u;
            nb |= ((fabsf(xv[k][0][3] - q2[1]) + fabsf(xv[k][1][3] - q2[2]) + fabsf(xv[k][2][3] - q2[3])) > THRESH) ? 8u : 0u;
            nib[k] = nb;
        }
#pragma unroll
        for (int k = 0; k < 4; ++k) {
            uint64_t w = pack16(nib[k]);
            if ((lane & 15) == 0) B[HALO + wave + 8 * k][lane >> 4] = w;
        }
        // halo rows (10): slots 0..7 one per wave, slots 8..9 on waves 0..1
        {
            const int slot = wave;
            const int gr   = (slot < 5) ? (r0 - HALO + slot) : (r0 + ROWS + (slot - 5));
            const int brow = (slot < 5) ? slot : (HALO + ROWS + (slot - 5));
            uint64_t w = pack16(mask_nib(X, bg, t, gr, col4));
            if ((lane & 15) == 0) B[brow][lane >> 4] = w;
        }
        if (tid < 128) {
            const int slot = 8 + wave;
            const int gr   = r0 + ROWS + (slot - 5);
            const int brow = HALO + ROWS + (slot - 5);
            uint64_t w = pack16(mask_nib(X, bg, t, gr, col4));
            if ((lane & 15) == 0) B[brow][lane >> 4] = w;
        }
        __syncthreads();   // the ONE barrier per tile

        // ---- phase 2: redundant all-wave in-register dilation (rows in lanes) ----
        uint64_t r_[4];
#pragma unroll
        for (int i = 0; i < 4; ++i) r_[i] = (lane < BROWS) ? B[lane][i] : 0ULL;
#pragma unroll
        for (int it = 0; it < 5; ++it) {
            uint64_t nr[4];
#pragma unroll
            for (int i = 0; i < 4; ++i) {
                uint64_t c  = r_[i];
                uint64_t l  = (i > 0) ? r_[i - 1] : 0ULL;
                uint64_t rr = (i < 3) ? r_[i + 1] : 0ULL;
                uint64_t u  = shfl64(c, lane - 1);   // lane0 wraps; masked below
                uint64_t d  = shfl64(c, lane + 1);   // lane63 wrap garbage stays >= lane 59
                u = (lane == 0) ? 0ULL : u;
                nr[i] = c | (c << 1) | (l >> 63) | (c >> 1) | (rr << 63) | u | d;
            }
#pragma unroll
            for (int i = 0; i < 4; ++i) r_[i] = nr[i];
        }

        // ---- phase 3: broadcast row word via shfl, apply, NT store ----
#pragma unroll
        for (int k = 0; k < 4; ++k) {
            const int row = wave + 8 * k;
            const int src = HALO + row;              // uniform per wave
            uint64_t t0 = shfl64(r_[0], src);
            uint64_t t1 = shfl64(r_[1], src);
            uint64_t t2 = shfl64(r_[2], src);
            uint64_t t3 = shfl64(r_[3], src);
            const int idx = lane >> 4;
            uint64_t lo = (idx & 1) ? t1 : t0;
            uint64_t hi = (idx & 1) ? t3 : t2;
            uint64_t w  = (idx & 2) ? hi : lo;
            uint32_t nb = (uint32_t)(w >> (4 * (lane & 15))) & 0xFu;
            float m0 = (float)(nb & 1u);
            float m1 = (float)((nb >> 1) & 1u);
            float m2 = (float)((nb >> 2) & 1u);
            float m3 = (float)((nb >> 3) & 1u);
            size_t pix = (size_t)t * FRAME + (size_t)(r0 + row) * WW + 4 * col4;
#pragma unroll
            for (int c = 0; c < 3; ++c) {
                nfloat4 v = xv[k][c];
                nfloat4 nv = { v[0] * m0, v[1] * m1, v[2] * m2, v[3] * m3 };
                __builtin_nontemporal_store(nv, (nfloat4*)(out + (size_t)c * PLANE + pix));
            }
        }
        // next rep's loads issue here -> overlap these stores
    }
}

extern "C" void kernel_launch(void* const* d_in, const int* in_sizes, int n_in,
                              void* d_out, int out_size, void* d_ws, size_t ws_size,
                              hipStream_t stream) {
    const float* X  = (const float*)d_in[0];
    const float* bg = (const float*)d_in[1];
    float* out = (float*)d_out;
    const int nblocks = TT * (TPF / REPEAT);   // 128 * 2 = 256 blocks, 1/CU
    fused_kernel<<<nblocks, 512, 0, stream>>>(X, bg, out);
}

// Round 8
// 40.750 us; speedup vs baseline: 1.0837x; 1.0837x over previous
//
#include <hip/hip_runtime.h>
#include <stdint.h>

#define TT 128
#define HH 256
#define WW 256
#define PLANE (TT*HH*WW)            // 8388608 elems / channel
#define FRAME (HH*WW)               // 65536 px / frame
#define ROWS 32                     // tile rows
#define TPF  (HH/ROWS)              // 8 tiles per frame
#define REPEAT 2                    // tiles per block (pipelined)
#define GROUPS (TPF/REPEAT)         // 4 block-groups per frame
#define HALO 5
#define BROWS (ROWS + 2*HALO)       // 42 buffered rows (fits one wave)
#define THRESH 0.5f

typedef float nfloat4 __attribute__((ext_vector_type(4)));

__device__ __forceinline__ uint64_t shfl64(uint64_t v, int src) {
    uint32_t lo = (uint32_t)v, hi = (uint32_t)(v >> 32);
    lo = __shfl(lo, src);
    hi = __shfl(hi, src);
    return ((uint64_t)hi << 32) | lo;
}

// OR-combine 16 lanes' nibbles into one u64 row-word. col = 64*(l>>4)+4*(l&15)+p.
__device__ __forceinline__ uint64_t pack16(uint32_t nib) {
    int lane = threadIdx.x & 63;
    uint64_t v = (uint64_t)nib << (4 * (lane & 15));
    v |= __shfl_xor(v, 1);
    v |= __shfl_xor(v, 2);
    v |= __shfl_xor(v, 4);
    v |= __shfl_xor(v, 8);
    return v;
}

// nib from 3-channel X vec4s + background row (same f32 add order as numpy).
__device__ __forceinline__ uint32_t nib_from(nfloat4 x0, nfloat4 x1, nfloat4 x2,
                                             const float* __restrict__ bg,
                                             int gr, int col4) {
    const nfloat4* bp = (const nfloat4*)(bg + ((size_t)gr * WW + 4 * col4) * 3);
    nfloat4 q0 = bp[0], q1 = bp[1], q2 = bp[2];
    uint32_t nib = 0;
    nib |= ((fabsf(x0[0] - q0[0]) + fabsf(x1[0] - q0[1]) + fabsf(x2[0] - q0[2])) > THRESH) ? 1u : 0u;
    nib |= ((fabsf(x0[1] - q0[3]) + fabsf(x1[1] - q1[0]) + fabsf(x2[1] - q1[1])) > THRESH) ? 2u : 0u;
    nib |= ((fabsf(x0[2] - q1[2]) + fabsf(x1[2] - q1[3]) + fabsf(x2[2] - q2[0])) > THRESH) ? 4u : 0u;
    nib |= ((fabsf(x0[3] - q2[1]) + fabsf(x1[3] - q2[2]) + fabsf(x2[3] - q2[3])) > THRESH) ? 8u : 0u;
    return nib;
}

__global__ __launch_bounds__(512) void fused_kernel(const float* __restrict__ X,
                                                    const float* __restrict__ bg,
                                                    float* __restrict__ out) {
    __shared__ uint64_t mbuf[2][BROWS][4];      // double-buffered mask bits, 2688 B
    const int t    = blockIdx.x >> 2;           // frame
    const int j0   = (blockIdx.x & (GROUPS - 1)) * REPEAT;
    const int tid  = threadIdx.x;
    const int lane = tid & 63;
    const int wave = tid >> 6;                  // 0..7
    const int col4 = lane;                      // float4-column 0..63

#pragma unroll
    for (int rep = 0; rep < REPEAT; ++rep) {
        const int r0 = (j0 + rep) * ROWS;
        uint64_t (*B)[4] = mbuf[rep & 1];       // compile-time after unroll

        // ---- phase L: issue ALL X loads (main tile + halo) back-to-back ----
        nfloat4 xv[4][3];
#pragma unroll
        for (int k = 0; k < 4; ++k) {
            const int gr = r0 + wave + 8 * k;
            size_t pix = (size_t)t * FRAME + (size_t)gr * WW + 4 * col4;
            xv[k][0] = *(const nfloat4*)(X + pix);
            xv[k][1] = *(const nfloat4*)(X + (size_t)PLANE + pix);
            xv[k][2] = *(const nfloat4*)(X + 2 * (size_t)PLANE + pix);
        }
        // halo pass A: slots 0..7 (one per wave); pass B: slots 8..9 (waves 0..1)
        const int slotA = wave;
        const int grA   = (slotA < 5) ? (r0 - HALO + slotA) : (r0 + ROWS + (slotA - 5));
        const int browA = (slotA < 5) ? slotA : (HALO + ROWS + (slotA - 5));
        const bool okA  = (grA >= 0) && (grA < HH);
        nfloat4 ha0 = 0, ha1 = 0, ha2 = 0;
        if (okA) {
            size_t pix = (size_t)t * FRAME + (size_t)grA * WW + 4 * col4;
            ha0 = *(const nfloat4*)(X + pix);
            ha1 = *(const nfloat4*)(X + (size_t)PLANE + pix);
            ha2 = *(const nfloat4*)(X + 2 * (size_t)PLANE + pix);
        }
        const int grB   = r0 + ROWS + 3 + wave;             // slots 8..9
        const int browB = HALO + ROWS + 3 + wave;
        const bool okB  = (wave < 2) && (grB < HH);
        nfloat4 hb0 = 0, hb1 = 0, hb2 = 0;
        if (okB) {
            size_t pix = (size_t)t * FRAME + (size_t)grB * WW + 4 * col4;
            hb0 = *(const nfloat4*)(X + pix);
            hb1 = *(const nfloat4*)(X + (size_t)PLANE + pix);
            hb2 = *(const nfloat4*)(X + 2 * (size_t)PLANE + pix);
        }

        // ---- phase C: bg loads + nibs + LDS writes ----
#pragma unroll
        for (int k = 0; k < 4; ++k) {
            const int gr = r0 + wave + 8 * k;
            uint64_t w = pack16(nib_from(xv[k][0], xv[k][1], xv[k][2], bg, gr, col4));
            if ((lane & 15) == 0) B[HALO + wave + 8 * k][lane >> 4] = w;
        }
        {
            uint32_t nb = okA ? nib_from(ha0, ha1, ha2, bg, grA, col4) : 0u;
            uint64_t w = pack16(nb);
            if ((lane & 15) == 0) B[browA][lane >> 4] = w;
        }
        if (wave < 2) {
            uint32_t nb = okB ? nib_from(hb0, hb1, hb2, bg, grB, col4) : 0u;
            uint64_t w = pack16(nb);
            if ((lane & 15) == 0) B[browB][lane >> 4] = w;
        }
        __syncthreads();

        // ---- phase D: 5 cross-dilation iterations, ONE wave, rows in lanes ----
        if (wave == 0) {
            uint64_t r_[4];
#pragma unroll
            for (int i = 0; i < 4; ++i) r_[i] = (lane < BROWS) ? B[lane][i] : 0ULL;
#pragma unroll
            for (int it = 0; it < 5; ++it) {
                uint64_t nr[4];
#pragma unroll
                for (int i = 0; i < 4; ++i) {
                    uint64_t c  = r_[i];
                    uint64_t l  = (i > 0) ? r_[i - 1] : 0ULL;
                    uint64_t rr = (i < 3) ? r_[i + 1] : 0ULL;
                    uint64_t u  = shfl64(c, lane - 1);   // lane0 wraps; masked below
                    uint64_t d  = shfl64(c, lane + 1);   // lane41 gets lane42 (=0)
                    u = (lane == 0) ? 0ULL : u;
                    nr[i] = c | (c << 1) | (l >> 63) | (c >> 1) | (rr << 63) | u | d;
                }
#pragma unroll
                for (int i = 0; i < 4; ++i) r_[i] = nr[i];
            }
            if (lane >= HALO && lane < HALO + ROWS) {
#pragma unroll
                for (int i = 0; i < 4; ++i) B[lane][i] = r_[i];
            }
        }
        __syncthreads();

        // ---- phase S: apply mask to register tile, NT store ----
#pragma unroll
        for (int k = 0; k < 4; ++k) {
            const int row = wave + 8 * k;
            uint64_t w = B[HALO + row][col4 >> 4];
            uint32_t nb = (uint32_t)(w >> (4 * (col4 & 15))) & 0xFu;
            float m0 = (float)(nb & 1u);
            float m1 = (float)((nb >> 1) & 1u);
            float m2 = (float)((nb >> 2) & 1u);
            float m3 = (float)((nb >> 3) & 1u);
            size_t pix = (size_t)t * FRAME + (size_t)(r0 + row) * WW + 4 * col4;
#pragma unroll
            for (int c = 0; c < 3; ++c) {
                nfloat4 v = xv[k][c];
                nfloat4 nv = { v[0] * m0, v[1] * m1, v[2] * m2, v[3] * m3 };
                __builtin_nontemporal_store(nv, (nfloat4*)(out + (size_t)c * PLANE + pix));
            }
        }
        // next rep's phase-L loads issue here -> overlap these NT stores
    }
}

extern "C" void kernel_launch(void* const* d_in, const int* in_sizes, int n_in,
                              void* d_out, int out_size, void* d_ws, size_t ws_size,
                              hipStream_t stream) {
    const float* X  = (const float*)d_in[0];
    const float* bg = (const float*)d_in[1];
    float* out = (float*)d_out;
    const int nblocks = TT * GROUPS;   // 128 * 4 = 512 blocks -> 2 blocks/CU
    fused_kernel<<<nblocks, 512, 0, stream>>>(X, bg, out);
}

// Round 9
// 39.198 us; speedup vs baseline: 1.1266x; 1.0396x over previous
//
#include <hip/hip_runtime.h>
#include <stdint.h>

#define TT 128
#define HH 256
#define WW 256
#define PLANE (TT*HH*WW)            // 8388608 elems / channel
#define FRAME (HH*WW)               // 65536 px / frame
#define ROWS 32                     // tile rows per block
#define HALO 5
#define BROWS (ROWS + 2*HALO)       // 42 buffered rows (fits one wave)
#define THRESH 0.5f

typedef float nfloat4 __attribute__((ext_vector_type(4)));

__device__ __forceinline__ uint64_t shfl64(uint64_t v, int src) {
    uint32_t lo = (uint32_t)v, hi = (uint32_t)(v >> 32);
    lo = __shfl(lo, src);
    hi = __shfl(hi, src);
    return ((uint64_t)hi << 32) | lo;
}

// OR-combine 16 lanes' nibbles into one u64 row-word. col = 64*(l>>4)+4*(l&15)+p.
__device__ __forceinline__ uint64_t pack16(uint32_t nib) {
    int lane = threadIdx.x & 63;
    uint64_t v = (uint64_t)nib << (4 * (lane & 15));
    v |= __shfl_xor(v, 1);
    v |= __shfl_xor(v, 2);
    v |= __shfl_xor(v, 4);
    v |= __shfl_xor(v, 8);
    return v;
}

// Mask nibble for 4 pixels at (frame t, row gr, cols 4*col4..+3).
// Out-of-frame rows -> 0. Same f32 add order as numpy: (d0+d1)+d2.
__device__ __forceinline__ uint32_t mask_nib(const float* __restrict__ X,
                                             const float* __restrict__ bg,
                                             int t, int gr, int col4) {
    if (gr < 0 || gr >= HH) return 0u;
    size_t pix = (size_t)t * FRAME + (size_t)gr * WW + 4 * col4;
    nfloat4 x0 = *(const nfloat4*)(X + pix);
    nfloat4 x1 = *(const nfloat4*)(X + (size_t)PLANE + pix);
    nfloat4 x2 = *(const nfloat4*)(X + 2 * (size_t)PLANE + pix);
    const nfloat4* bp = (const nfloat4*)(bg + ((size_t)gr * WW + 4 * col4) * 3);
    nfloat4 q0 = bp[0], q1 = bp[1], q2 = bp[2];
    uint32_t nib = 0;
    nib |= ((fabsf(x0[0] - q0[0]) + fabsf(x1[0] - q0[1]) + fabsf(x2[0] - q0[2])) > THRESH) ? 1u : 0u;
    nib |= ((fabsf(x0[1] - q0[3]) + fabsf(x1[1] - q1[0]) + fabsf(x2[1] - q1[1])) > THRESH) ? 2u : 0u;
    nib |= ((fabsf(x0[2] - q1[2]) + fabsf(x1[2] - q1[3]) + fabsf(x2[2] - q2[0])) > THRESH) ? 4u : 0u;
    nib |= ((fabsf(x0[3] - q2[1]) + fabsf(x1[3] - q2[2]) + fabsf(x2[3] - q2[3])) > THRESH) ? 8u : 0u;
    return nib;
}

__global__ __launch_bounds__(512) void fused_kernel(const float* __restrict__ X,
                                                    const float* __restrict__ bg,
                                                    float* __restrict__ out) {
    __shared__ uint64_t B[BROWS][5];            // padded: 40 B row stride (4-way max)
    const int t    = blockIdx.x >> 3;           // frame
    const int j    = blockIdx.x & 7;            // row-tile within frame
    const int r0   = j * ROWS;
    const int tid  = threadIdx.x;
    const int lane = tid & 63;
    const int wave = tid >> 6;                  // 0..7
    const int col4 = lane;                      // float4-column 0..63

    // ---- phase 1: main tile — load X into regs, mask bits into LDS ----
    nfloat4 xv[4][3];
#pragma unroll
    for (int k = 0; k < 4; ++k) {
        const int gr = r0 + wave + 8 * k;
        size_t pix = (size_t)t * FRAME + (size_t)gr * WW + 4 * col4;
        xv[k][0] = *(const nfloat4*)(X + pix);
        xv[k][1] = *(const nfloat4*)(X + (size_t)PLANE + pix);
        xv[k][2] = *(const nfloat4*)(X + 2 * (size_t)PLANE + pix);
        const nfloat4* bp = (const nfloat4*)(bg + ((size_t)gr * WW + 4 * col4) * 3);
        nfloat4 q0 = bp[0], q1 = bp[1], q2 = bp[2];
        uint32_t nib = 0;
        nib |= ((fabsf(xv[k][0][0] - q0[0]) + fabsf(xv[k][1][0] - q0[1]) + fabsf(xv[k][2][0] - q0[2])) > THRESH) ? 1u : 0u;
        nib |= ((fabsf(xv[k][0][1] - q0[3]) + fabsf(xv[k][1][1] - q1[0]) + fabsf(xv[k][2][1] - q1[1])) > THRESH) ? 2u : 0u;
        nib |= ((fabsf(xv[k][0][2] - q1[2]) + fabsf(xv[k][1][2] - q1[3]) + fabsf(xv[k][2][2] - q2[0])) > THRESH) ? 4u : 0u;
        nib |= ((fabsf(xv[k][0][3] - q2[1]) + fabsf(xv[k][1][3] - q2[2]) + fabsf(xv[k][2][3] - q2[3])) > THRESH) ? 8u : 0u;
        uint64_t w = pack16(nib);
        if ((lane & 15) == 0) B[HALO + wave + 8 * k][lane >> 4] = w;
    }

    // ---- phase 1b: halo rows (10): slots 0..7 one per wave, 8..9 on waves 0..1 ----
    {
        const int slot = wave;
        const int gr   = (slot < 5) ? (r0 - HALO + slot) : (r0 + ROWS + (slot - 5));
        const int brow = (slot < 5) ? slot : (HALO + ROWS + (slot - 5));
        uint64_t w = pack16(mask_nib(X, bg, t, gr, col4));
        if ((lane & 15) == 0) B[brow][lane >> 4] = w;
    }
    if (tid < 128) {
        const int slot = 8 + wave;
        const int gr   = r0 + ROWS + (slot - 5);
        const int brow = HALO + ROWS + (slot - 5);
        uint64_t w = pack16(mask_nib(X, bg, t, gr, col4));
        if ((lane & 15) == 0) B[brow][lane >> 4] = w;
    }
    __syncthreads();   // the ONLY barrier

    // ---- phase 2: redundant all-wave in-register dilation (rows in lanes) ----
    uint64_t r_[4];
#pragma unroll
    for (int i = 0; i < 4; ++i) r_[i] = (lane < BROWS) ? B[lane][i] : 0ULL;
#pragma unroll
    for (int it = 0; it < 5; ++it) {
        uint64_t nr[4];
#pragma unroll
        for (int i = 0; i < 4; ++i) {
            uint64_t c  = r_[i];
            uint64_t l  = (i > 0) ? r_[i - 1] : 0ULL;
            uint64_t rr = (i < 3) ? r_[i + 1] : 0ULL;
            uint64_t u  = shfl64(c, lane - 1);   // lane0 wraps; masked below
            uint64_t d  = shfl64(c, lane + 1);   // lane63 wrap garbage stays >= lane 59
            u = (lane == 0) ? 0ULL : u;
            nr[i] = c | (c << 1) | (l >> 63) | (c >> 1) | (rr << 63) | u | d;
        }
#pragma unroll
        for (int i = 0; i < 4; ++i) r_[i] = nr[i];
    }

    // ---- phase 3: broadcast own rows' words via shfl, apply, NT store ----
#pragma unroll
    for (int k = 0; k < 4; ++k) {
        const int row = wave + 8 * k;
        const int src = HALO + row;              // uniform per wave
        uint64_t t0 = shfl64(r_[0], src);
        uint64_t t1 = shfl64(r_[1], src);
        uint64_t t2 = shfl64(r_[2], src);
        uint64_t t3 = shfl64(r_[3], src);
        const int idx = col4 >> 4;
        uint64_t lo = (idx & 1) ? t1 : t0;
        uint64_t hi = (idx & 1) ? t3 : t2;
        uint64_t w  = (idx & 2) ? hi : lo;
        uint32_t nb = (uint32_t)(w >> (4 * (col4 & 15))) & 0xFu;
        float m0 = (float)(nb & 1u);
        float m1 = (float)((nb >> 1) & 1u);
        float m2 = (float)((nb >> 2) & 1u);
        float m3 = (float)((nb >> 3) & 1u);
        size_t pix = (size_t)t * FRAME + (size_t)(r0 + row) * WW + 4 * col4;
#pragma unroll
        for (int c = 0; c < 3; ++c) {
            nfloat4 v = xv[k][c];
            nfloat4 nv = { v[0] * m0, v[1] * m1, v[2] * m2, v[3] * m3 };
            __builtin_nontemporal_store(nv, (nfloat4*)(out + (size_t)c * PLANE + pix));
        }
    }
}

extern "C" void kernel_launch(void* const* d_in, const int* in_sizes, int n_in,
                              void* d_out, int out_size, void* d_ws, size_t ws_size,
                              hipStream_t stream) {
    const float* X  = (const float*)d_in[0];
    const float* bg = (const float*)d_in[1];
    float* out = (float*)d_out;
    const int nblocks = TT * (HH / ROWS);   // 128 * 8 = 1024
    fused_kernel<<<nblocks, 512, 0, stream>>>(X, bg, out);
}